// Round 6
// baseline (153.451 us; speedup 1.0000x reference)
//
#include <hip/hip_runtime.h>

typedef short short8 __attribute__((ext_vector_type(8)));
typedef float f32x4 __attribute__((ext_vector_type(4)));

#define NTOK (8 * 16 * 32 * 32)  // 131072 tokens
#define NE 1024
#define ED 64
#define TPB 256
#define MBLK 256                 // tokens per block = 4 waves x 64
#define NMF 4                    // m-frags per wave (64 tokens)
#define WKEY (1 << 18)           // candidate window in key units (~3.9e-3 in dist)
#define SCALE (-131072.0f)       // -2^17: exact po2 scale — applied to B ONLY

__device__ __forceinline__ unsigned short bf16_rtne(float f) {
    unsigned u = __float_as_uint(f);
    return (unsigned short)((u + 0x7FFFu + ((u >> 16) & 1u)) >> 16);
}
__device__ __forceinline__ float bf16_to_f32(unsigned short h) {
    return __uint_as_float(((unsigned)h) << 16);
}

// ---- prep: B-fragments (hi/lo bf16, -2^17-scaled, MFMA order), coalesced
//      scaled s2 (approx path), and s2x = EXACT ||e||^2 with the same
//      accumulator order as the recheck path (bit-identical reuse). ----
__global__ __launch_bounds__(128) void vq_prep(
    const float* __restrict__ emb,
    unsigned short* __restrict__ bfH,
    unsigned short* __restrict__ bfL,
    float* __restrict__ s2s,
    float* __restrict__ s2x)
{
    const int f = blockIdx.x * 128 + threadIdx.x;  // 0..8191 fragment id
    const int col = f & 15;
    const int quad = (f >> 4) & 3;
    const int kb = (f >> 6) & 1;
    const int nt = f >> 7;
    const int e = nt * 16 + col;
    const int k0 = kb * 32 + quad * 8;

    const float* p = emb + (size_t)e * ED + k0;
    float4 v0 = *(const float4*)p;
    float4 v1 = *(const float4*)(p + 4);
    float vs[8] = {v0.x, v0.y, v0.z, v0.w, v1.x, v1.y, v1.z, v1.w};
    short8 h, l;
#pragma unroll
    for (int j = 0; j < 8; ++j) {
        float x = vs[j] * SCALE;              // exact po2 scaling (B side only!)
        unsigned short hb = bf16_rtne(x);
        float hf = bf16_to_f32(hb);
        unsigned short lb = bf16_rtne(x - hf);
        h[j] = (short)hb;
        l[j] = (short)lb;
    }
    *(short8*)&bfH[(size_t)f * 8] = h;
    *(short8*)&bfL[(size_t)f * 8] = l;

    // scaled s2 for the approx keys (order-insensitive: feeds approx path only)
    if (f < 4096) {
        const int row = f >> 2;
        const float4* rp = (const float4*)(emb + (size_t)row * ED + (f & 3) * 16);
        float4 a = rp[0], b = rp[1], c = rp[2], d = rp[3];
        float s = a.x * a.x + a.y * a.y + a.z * a.z + a.w * a.w
                + b.x * b.x + b.y * b.y + b.z * b.z + b.w * b.w
                + c.x * c.x + c.y * c.y + c.z * c.z + c.w * c.w
                + d.x * d.x + d.y * d.y + d.z * d.z + d.w * d.w;
        s += __shfl_xor(s, 1);
        s += __shfl_xor(s, 2);
        if ((f & 3) == 0) s2s[row] = s * 65536.0f;
    }

    // EXACT ||e||^2 — accumulator pattern identical to the recheck's s2 block
    if (f < NE) {
        const float* ep = emb + (size_t)f * ED;
        float q0 = 0.f, q1 = 0.f, q2 = 0.f, q3 = 0.f;
        float q4 = 0.f, q5 = 0.f, q6 = 0.f, q7 = 0.f;
        for (int d = 0; d < ED; d += 8) {
            float w0 = ep[d + 0], w1 = ep[d + 1], w2 = ep[d + 2], w3 = ep[d + 3];
            float w4 = ep[d + 4], w5 = ep[d + 5], w6 = ep[d + 6], w7 = ep[d + 7];
            q0 += w0 * w0; q1 += w1 * w1; q2 += w2 * w2; q3 += w3 * w3;
            q4 += w4 * w4; q5 += w5 * w5; q6 += w6 * w6; q7 += w7 * w7;
        }
        s2x[f] = ((q0 + q1) + (q2 + q3)) + ((q4 + q5) + (q6 + q7));
    }
}

// ---- main: R2 structure (NMF=4, best measured) + cheap recheck.
//      Phase B is the COMMON path (embeddings*0.02 => top-2 gap ~3e-4 << WKEY
//      window 3.9e-3), so it is optimized: s1 computed once per token-group
//      (same code order as before => bit-identical), s2 from the exact
//      precomputed table, both candidates' dot products fused in one
//      float4-vectorized pass (per-candidate accumulators unchanged). ----
__global__ void __launch_bounds__(TPB) vq_main(
    const float* __restrict__ z,
    const float* __restrict__ emb,
    const unsigned short* __restrict__ bfH,
    const unsigned short* __restrict__ bfL,
    const float* __restrict__ s2s_g,
    const float* __restrict__ s2x,
    float* __restrict__ zq_out,
    float* __restrict__ idx_out)
{
    __shared__ float s2L[NE];
    __shared__ int idx_lds[MBLK];

    const int tid = threadIdx.x;
    const int lane = tid & 63;
    const int wv = __builtin_amdgcn_readfirstlane(tid >> 6);
    const int col = lane & 15;
    const int quad = lane >> 4;
    const int blockTok = blockIdx.x * MBLK;

    for (int i = tid; i < NE; i += TPB) s2L[i] = s2s_g[i];

    // ---- A-fragments: 64 tokens per wave (4 m-frags), hi/lo bf16, UNSCALED ----
    short8 Ah[NMF][2], Al[NMF][2];
#pragma unroll
    for (int mf = 0; mf < NMF; ++mf) {
#pragma unroll
        for (int kf = 0; kf < 2; ++kf) {
            const float* zp = z + (size_t)(blockTok + wv * 64 + mf * 16 + col) * ED
                              + kf * 32 + quad * 8;
            float4 v0 = *(const float4*)zp;
            float4 v1 = *(const float4*)(zp + 4);
            float vs[8] = {v0.x, v0.y, v0.z, v0.w, v1.x, v1.y, v1.z, v1.w};
            short8 h, l;
#pragma unroll
            for (int j = 0; j < 8; ++j) {
                float x = vs[j];              // NO scale on A
                unsigned short hb = bf16_rtne(x);
                float hf = bf16_to_f32(hb);
                unsigned short lb = bf16_rtne(x - hf);
                h[j] = (short)hb;
                l[j] = (short)lb;
            }
            Ah[mf][kf] = h;
            Al[mf][kf] = l;
        }
    }

    int aK[NMF][4], bK[NMF][4];
#pragma unroll
    for (int mf = 0; mf < NMF; ++mf)
#pragma unroll
        for (int r = 0; r < 4; ++r) { aK[mf][r] = 0x7FFFFFFF; bK[mf][r] = 0x7FFFFFFF; }

    // B-fragment streams: per nt-slice, 128 fragments of 16B; lane's frags are
    // u4[nt*128 + lane] (k-frag 0) and u4[nt*128 + 64 + lane] (k-frag 1).
    const uint4* u4H = (const uint4*)bfH;
    const uint4* u4L = (const uint4*)bfL;

    // prologue: load slice 0
    uint4 cB0 = u4H[lane];
    uint4 cB1 = u4H[64 + lane];
    uint4 cB2 = u4L[lane];
    uint4 cB3 = u4L[64 + lane];

    __syncthreads();  // s2L ready (only barrier before the epilogue)

    for (int nt = 0; nt < 64; ++nt) {
        // prefetch next slice (wrap: redundant re-load of slice 0, never consumed)
        const int nb = (((nt + 1) & 63) << 7) + lane;
        uint4 nB0 = u4H[nb];
        uint4 nB1 = u4H[nb + 64];
        uint4 nB2 = u4L[nb];
        uint4 nB3 = u4L[nb + 64];

        short8 Bh0 = __builtin_bit_cast(short8, cB0);
        short8 Bh1 = __builtin_bit_cast(short8, cB1);
        short8 Bl0 = __builtin_bit_cast(short8, cB2);
        short8 Bl1 = __builtin_bit_cast(short8, cB3);

        const float s2v = s2L[nt * 16 + col];
        const int e = nt * 16 + col;
#pragma unroll
        for (int mf = 0; mf < NMF; ++mf) {
            f32x4 cc = {s2v, s2v, s2v, s2v};  // acc = s2*2^16 + A·(-2^17 e) = 2^16(s2-2g)
            cc = __builtin_amdgcn_mfma_f32_16x16x32_bf16(Ah[mf][0], Bh0, cc, 0, 0, 0);
            cc = __builtin_amdgcn_mfma_f32_16x16x32_bf16(Ah[mf][1], Bh1, cc, 0, 0, 0);
            cc = __builtin_amdgcn_mfma_f32_16x16x32_bf16(Al[mf][0], Bh0, cc, 0, 0, 0);
            cc = __builtin_amdgcn_mfma_f32_16x16x32_bf16(Al[mf][1], Bh1, cc, 0, 0, 0);
            cc = __builtin_amdgcn_mfma_f32_16x16x32_bf16(Ah[mf][0], Bl0, cc, 0, 0, 0);
            cc = __builtin_amdgcn_mfma_f32_16x16x32_bf16(Ah[mf][1], Bl1, cc, 0, 0, 0);
#pragma unroll
            for (int r = 0; r < 4; ++r) {
                int key = ((int)cc[r]) * 1024 + e;  // unique, monotone, tie->low e
                const int a0 = aK[mf][r];
                int t1 = min(a0, key);
                // bK' = min(bK, max(a0, key)) == med3(a0, bK, key) since a0<=bK
                int med;
                asm("v_med3_i32 %0, %1, %2, %3"
                    : "=v"(med) : "v"(a0), "v"(bK[mf][r]), "v"(key));
                bK[mf][r] = med;
                aK[mf][r] = t1;
            }
        }

        cB0 = nB0; cB1 = nB1; cB2 = nB2; cB3 = nB3;
    }

    // ---- phase B: resolve argmin per token (16-lane groups) ----
#pragma unroll
    for (int mf = 0; mf < NMF; ++mf) {
#pragma unroll
        for (int r = 0; r < 4; ++r) {
            const int a0 = aK[mf][r], b0 = bK[mf][r];
            int A = a0, B = b0;
#pragma unroll
            for (int off = 1; off < 16; off <<= 1) {
                int A2 = __shfl_xor(A, off);
                int B2 = __shfl_xor(B, off);
                int lo = min(A, A2), hi = max(A, A2);
                B = min(min(B, B2), hi);
                A = lo;
            }
            int winner = A & 1023;
            if (B - A <= WKEY) {  // contested (common case): exact fp32 re-check
                const int t = blockTok + wv * 64 + mf * 16 + quad * 4 + r;
                const float4* ztp = (const float4*)(z + (size_t)t * ED);

                // s1 = ||z_t||^2 — identical accumulator order to the original
                // exact_dist (computed ONCE, shared by both candidates).
                float r0 = 0.f, r1 = 0.f, r2 = 0.f, r3 = 0.f;
                float r4 = 0.f, r5 = 0.f, r6 = 0.f, r7 = 0.f;
#pragma unroll
                for (int d8 = 0; d8 < ED / 8; ++d8) {
                    float4 u0 = ztp[d8 * 2 + 0];
                    float4 u1 = ztp[d8 * 2 + 1];
                    r0 += u0.x * u0.x;
                    r1 += u0.y * u0.y;
                    r2 += u0.z * u0.z;
                    r3 += u0.w * u0.w;
                    r4 += u1.x * u1.x;
                    r5 += u1.y * u1.y;
                    r6 += u1.z * u1.z;
                    r7 += u1.w * u1.w;
                }
                const float s1 = ((r0 + r1) + (r2 + r3)) + ((r4 + r5) + (r6 + r7));

                // fused dual dot product; per-candidate accumulator chains are
                // identical to the original exact_dist g-loop (d += 4, fmaf).
                const int ea = a0 & 1023, eb = b0 & 1023;
                const float4* epa = (const float4*)(emb + (size_t)ea * ED);
                const float4* epb = (const float4*)(emb + (size_t)eb * ED);
                float ga0 = 0.f, ga1 = 0.f, ga2 = 0.f, ga3 = 0.f;
                float gb0 = 0.f, gb1 = 0.f, gb2 = 0.f, gb3 = 0.f;
#pragma unroll
                for (int d4 = 0; d4 < ED / 4; ++d4) {
                    float4 zz = ztp[d4];
                    float4 va = epa[d4];
                    float4 vb = epb[d4];
                    ga0 = fmaf(zz.x, va.x, ga0);
                    ga1 = fmaf(zz.y, va.y, ga1);
                    ga2 = fmaf(zz.z, va.z, ga2);
                    ga3 = fmaf(zz.w, va.w, ga3);
                    gb0 = fmaf(zz.x, vb.x, gb0);
                    gb1 = fmaf(zz.y, vb.y, gb1);
                    gb2 = fmaf(zz.z, vb.z, gb2);
                    gb3 = fmaf(zz.w, vb.w, gb3);
                }
                const float ga = (ga0 + ga1) + (ga2 + ga3);
                const float gb = (gb0 + gb1) + (gb2 + gb3);
                const float da = (s1 + s2x[ea]) - 2.0f * ga;
                const float db = (s1 + s2x[eb]) - 2.0f * gb;

                // replicate the original compare sequence exactly
                float dbest = 3.4e38f;
                int ibest = 1 << 30;
                if (a0 <= A + WKEY) { dbest = da; ibest = ea; }
                if (b0 <= A + WKEY &&
                    (db < dbest || (db == dbest && eb < ibest))) {
                    dbest = db; ibest = eb;
                }
#pragma unroll
                for (int off = 1; off < 16; off <<= 1) {
                    float d2 = __shfl_xor(dbest, off);
                    int i2 = __shfl_xor(ibest, off);
                    if (d2 < dbest || (d2 == dbest && i2 < ibest)) { dbest = d2; ibest = i2; }
                }
                winner = ibest;
            }
            if (col == 0) idx_lds[wv * 64 + mf * 16 + quad * 4 + r] = winner;
        }
    }

    __syncthreads();

    // ---- outputs ----
    idx_out[blockTok + tid] = (float)idx_lds[tid];
    const float4* emb_f4 = (const float4*)emb;
    float4* zq_f4 = (float4*)zq_out;
#pragma unroll
    for (int i = 0; i < MBLK * 16 / TPB; ++i) {  // 16 iters
        int item = tid + i * TPB;
        int tl = item >> 4, f4 = item & 15;
        int wi = idx_lds[tl];
        zq_f4[(size_t)(blockTok + tl) * 16 + f4] = emb_f4[(size_t)wi * 16 + f4];
    }
}

extern "C" void kernel_launch(void* const* d_in, const int* in_sizes, int n_in,
                              void* d_out, int out_size, void* d_ws, size_t ws_size,
                              hipStream_t stream) {
    const float* z = (const float*)d_in[0];
    const float* emb = (const float*)d_in[1];
    float* out = (float*)d_out;
    float* zq = out;                       // 131072*64 floats
    float* idx = out + (size_t)NTOK * ED;  // 131072 floats

    // ws layout: s2s (4KB) | s2x (4KB) | bfH (128KB) | bfL (128KB)
    char* ws = (char*)d_ws;
    float* s2s = (float*)ws;
    float* s2x = (float*)(ws + 4096);
    unsigned short* bfH = (unsigned short*)(ws + 8192);
    unsigned short* bfL = (unsigned short*)(ws + 8192 + 131072);

    vq_prep<<<64, 128, 0, stream>>>(emb, bfH, bfL, s2s, s2x);
    vq_main<<<NTOK / MBLK, TPB, 0, stream>>>(z, emb, bfH, bfL, s2s, s2x, zq, idx);
}

// Round 7
// 146.013 us; speedup vs baseline: 1.0509x; 1.0509x over previous
//
#include <hip/hip_runtime.h>

typedef short short8 __attribute__((ext_vector_type(8)));
typedef float f32x4 __attribute__((ext_vector_type(4)));

#define NTOK (8 * 16 * 32 * 32)  // 131072 tokens
#define NE 1024
#define ED 64
#define TPB 256
#define MBLK 256                 // tokens per block = 4 waves x 64
#define NMF 4                    // m-frags per wave (64 tokens)
#define WKEY (1 << 18)           // candidate window in key units (~3.9e-3 in dist)
#define SCALE (-131072.0f)       // -2^17: exact po2 scale — applied to B ONLY

__device__ __forceinline__ unsigned short bf16_rtne(float f) {
    unsigned u = __float_as_uint(f);
    return (unsigned short)((u + 0x7FFFu + ((u >> 16) & 1u)) >> 16);
}
__device__ __forceinline__ float bf16_to_f32(unsigned short h) {
    return __uint_as_float(((unsigned)h) << 16);
}

// EXACT distance — identical structure/order to the R1 kernel (absmax 0 vs numpy).
__device__ float exact_dist(const float* __restrict__ z, const float* __restrict__ emb,
                            int t, int e) {
    const float* zt = z + (size_t)t * ED;
    const float* ep = emb + (size_t)e * ED;
    float r0 = 0.f, r1 = 0.f, r2 = 0.f, r3 = 0.f;
    float r4 = 0.f, r5 = 0.f, r6 = 0.f, r7 = 0.f;
    for (int d = 0; d < ED; d += 8) {
        r0 += zt[d + 0] * zt[d + 0];
        r1 += zt[d + 1] * zt[d + 1];
        r2 += zt[d + 2] * zt[d + 2];
        r3 += zt[d + 3] * zt[d + 3];
        r4 += zt[d + 4] * zt[d + 4];
        r5 += zt[d + 5] * zt[d + 5];
        r6 += zt[d + 6] * zt[d + 6];
        r7 += zt[d + 7] * zt[d + 7];
    }
    float s1 = ((r0 + r1) + (r2 + r3)) + ((r4 + r5) + (r6 + r7));
    float q0 = 0.f, q1 = 0.f, q2 = 0.f, q3 = 0.f;
    float q4 = 0.f, q5 = 0.f, q6 = 0.f, q7 = 0.f;
    for (int d = 0; d < ED; d += 8) {
        float v0 = ep[d + 0], v1 = ep[d + 1], v2 = ep[d + 2], v3 = ep[d + 3];
        float v4 = ep[d + 4], v5 = ep[d + 5], v6 = ep[d + 6], v7 = ep[d + 7];
        q0 += v0 * v0; q1 += v1 * v1; q2 += v2 * v2; q3 += v3 * v3;
        q4 += v4 * v4; q5 += v5 * v5; q6 += v6 * v6; q7 += v7 * v7;
    }
    float s2 = ((q0 + q1) + (q2 + q3)) + ((q4 + q5) + (q6 + q7));
    float a0 = 0.f, a1 = 0.f, a2 = 0.f, a3 = 0.f;
    for (int d = 0; d < ED; d += 4) {
        a0 = fmaf(zt[d + 0], ep[d + 0], a0);
        a1 = fmaf(zt[d + 1], ep[d + 1], a1);
        a2 = fmaf(zt[d + 2], ep[d + 2], a2);
        a3 = fmaf(zt[d + 3], ep[d + 3], a3);
    }
    float g = (a0 + a1) + (a2 + a3);
    return (s1 + s2) - 2.0f * g;
}

// ---- prep: unchanged (B-fragments hi/lo bf16, -2^17-scaled, MFMA order; s2) ----
__global__ __launch_bounds__(128) void vq_prep(
    const float* __restrict__ emb,
    unsigned short* __restrict__ bfH,
    unsigned short* __restrict__ bfL,
    float* __restrict__ s2s)
{
    const int f = blockIdx.x * 128 + threadIdx.x;  // 0..8191 fragment id
    const int col = f & 15;
    const int quad = (f >> 4) & 3;
    const int kb = (f >> 6) & 1;
    const int nt = f >> 7;
    const int e = nt * 16 + col;
    const int k0 = kb * 32 + quad * 8;

    const float* p = emb + (size_t)e * ED + k0;
    float4 v0 = *(const float4*)p;
    float4 v1 = *(const float4*)(p + 4);
    float vs[8] = {v0.x, v0.y, v0.z, v0.w, v1.x, v1.y, v1.z, v1.w};
    short8 h, l;
#pragma unroll
    for (int j = 0; j < 8; ++j) {
        float x = vs[j] * SCALE;              // exact po2 scaling (B side only!)
        unsigned short hb = bf16_rtne(x);
        float hf = bf16_to_f32(hb);
        unsigned short lb = bf16_rtne(x - hf);
        h[j] = (short)hb;
        l[j] = (short)lb;
    }
    *(short8*)&bfH[(size_t)f * 8] = h;
    *(short8*)&bfL[(size_t)f * 8] = l;

    if (f < 4096) {
        const int row = f >> 2;
        const float4* rp = (const float4*)(emb + (size_t)row * ED + (f & 3) * 16);
        float4 a = rp[0], b = rp[1], c = rp[2], d = rp[3];
        float s = a.x * a.x + a.y * a.y + a.z * a.z + a.w * a.w
                + b.x * b.x + b.y * b.y + b.z * b.z + b.w * b.w
                + c.x * c.x + c.y * c.y + c.z * c.z + c.w * c.w
                + d.x * d.x + d.y * d.y + d.z * d.z + d.w * d.w;
        s += __shfl_xor(s, 1);
        s += __shfl_xor(s, 2);
        if ((f & 3) == 0) s2s[row] = s * 65536.0f;
    }
}

// ---- main: R2 config (NMF=4, 2 blocks/CU, best measured) with the MFMA
//      dependency graph restructured. R1/R2/R5 all had 8 acc-chains/SIMD and
//      all plateaued at ~80us with MfmaUtil ~26% = 2x465/3580 — the 6-deep
//      dependent chains were emitted serially (inline-asm med3 between chains
//      pinned the schedule). Here: each chain is split into two 3-deep halves
//      (ccA: k-frag0 terms, ccB: k-frag1 terms) and MFMAs are emitted
//      TERM-MAJOR, so program order gives same-chain dependency distance of
//      8 MFMAs (~155 cyc) — no scheduler heroics needed. Key updates are
//      plain min/max (no asm), batched after the MFMA block. ----
__global__ void __launch_bounds__(TPB) vq_main(
    const float* __restrict__ z,
    const float* __restrict__ emb,
    const unsigned short* __restrict__ bfH,
    const unsigned short* __restrict__ bfL,
    const float* __restrict__ s2s_g,
    float* __restrict__ zq_out,
    float* __restrict__ idx_out)
{
    __shared__ float s2L[NE];
    __shared__ int idx_lds[MBLK];

    const int tid = threadIdx.x;
    const int lane = tid & 63;
    const int wv = __builtin_amdgcn_readfirstlane(tid >> 6);
    const int col = lane & 15;
    const int quad = lane >> 4;
    const int blockTok = blockIdx.x * MBLK;

    for (int i = tid; i < NE; i += TPB) s2L[i] = s2s_g[i];

    // ---- A-fragments: 64 tokens per wave (4 m-frags), hi/lo bf16, UNSCALED ----
    short8 Ah[NMF][2], Al[NMF][2];
#pragma unroll
    for (int mf = 0; mf < NMF; ++mf) {
#pragma unroll
        for (int kf = 0; kf < 2; ++kf) {
            const float* zp = z + (size_t)(blockTok + wv * 64 + mf * 16 + col) * ED
                              + kf * 32 + quad * 8;
            float4 v0 = *(const float4*)zp;
            float4 v1 = *(const float4*)(zp + 4);
            float vs[8] = {v0.x, v0.y, v0.z, v0.w, v1.x, v1.y, v1.z, v1.w};
            short8 h, l;
#pragma unroll
            for (int j = 0; j < 8; ++j) {
                float x = vs[j];              // NO scale on A
                unsigned short hb = bf16_rtne(x);
                float hf = bf16_to_f32(hb);
                unsigned short lb = bf16_rtne(x - hf);
                h[j] = (short)hb;
                l[j] = (short)lb;
            }
            Ah[mf][kf] = h;
            Al[mf][kf] = l;
        }
    }

    int aK[NMF][4], bK[NMF][4];
#pragma unroll
    for (int mf = 0; mf < NMF; ++mf)
#pragma unroll
        for (int r = 0; r < 4; ++r) { aK[mf][r] = 0x7FFFFFFF; bK[mf][r] = 0x7FFFFFFF; }

    // B-fragment streams: per nt-slice, 128 fragments of 16B; lane's frags are
    // u4[nt*128 + lane] (k-frag 0) and u4[nt*128 + 64 + lane] (k-frag 1).
    const uint4* u4H = (const uint4*)bfH;
    const uint4* u4L = (const uint4*)bfL;

    // prologue: load slice 0
    uint4 cB0 = u4H[lane];
    uint4 cB1 = u4H[64 + lane];
    uint4 cB2 = u4L[lane];
    uint4 cB3 = u4L[64 + lane];

    __syncthreads();  // s2L ready (only barrier before the epilogue)

    for (int nt = 0; nt < 64; ++nt) {
        // prefetch next slice (wrap: redundant re-load of slice 0, never consumed)
        const int nb = (((nt + 1) & 63) << 7) + lane;
        uint4 nB0 = u4H[nb];
        uint4 nB1 = u4H[nb + 64];
        uint4 nB2 = u4L[nb];
        uint4 nB3 = u4L[nb + 64];

        short8 Bh0 = __builtin_bit_cast(short8, cB0);
        short8 Bh1 = __builtin_bit_cast(short8, cB1);
        short8 Bl0 = __builtin_bit_cast(short8, cB2);
        short8 Bl1 = __builtin_bit_cast(short8, cB3);

        const float s2v = s2L[nt * 16 + col];
        const int e = nt * 16 + col;

        // 8 independent accumulator chains (2 per mf): ccA = s2v + k-frag0
        // terms, ccB = k-frag1 terms; cc = ccA + ccB at the end. The fp32
        // reorder shifts keys by ~2 cc-ULPs — 2% of the WKEY window.
        f32x4 ccA[NMF], ccB[NMF];
#pragma unroll
        for (int mf = 0; mf < NMF; ++mf) {
            ccA[mf] = (f32x4){s2v, s2v, s2v, s2v};
            ccB[mf] = (f32x4){0.f, 0.f, 0.f, 0.f};
        }
        // term-major: same-chain dependency distance = 8 MFMAs in program order
#pragma unroll
        for (int mf = 0; mf < NMF; ++mf)
            ccA[mf] = __builtin_amdgcn_mfma_f32_16x16x32_bf16(Ah[mf][0], Bh0, ccA[mf], 0, 0, 0);
#pragma unroll
        for (int mf = 0; mf < NMF; ++mf)
            ccB[mf] = __builtin_amdgcn_mfma_f32_16x16x32_bf16(Ah[mf][1], Bh1, ccB[mf], 0, 0, 0);
#pragma unroll
        for (int mf = 0; mf < NMF; ++mf)
            ccA[mf] = __builtin_amdgcn_mfma_f32_16x16x32_bf16(Al[mf][0], Bh0, ccA[mf], 0, 0, 0);
#pragma unroll
        for (int mf = 0; mf < NMF; ++mf)
            ccB[mf] = __builtin_amdgcn_mfma_f32_16x16x32_bf16(Al[mf][1], Bh1, ccB[mf], 0, 0, 0);
#pragma unroll
        for (int mf = 0; mf < NMF; ++mf)
            ccA[mf] = __builtin_amdgcn_mfma_f32_16x16x32_bf16(Ah[mf][0], Bl0, ccA[mf], 0, 0, 0);
#pragma unroll
        for (int mf = 0; mf < NMF; ++mf)
            ccB[mf] = __builtin_amdgcn_mfma_f32_16x16x32_bf16(Ah[mf][1], Bl1, ccB[mf], 0, 0, 0);

        // key updates, batched after all MFMAs; plain min/max (no asm barrier)
#pragma unroll
        for (int mf = 0; mf < NMF; ++mf) {
            f32x4 cc = ccA[mf] + ccB[mf];
#pragma unroll
            for (int r = 0; r < 4; ++r) {
                int key = ((int)cc[r]) * 1024 + e;  // unique, monotone, tie->low e
                const int a0 = aK[mf][r];
                aK[mf][r] = min(a0, key);
                bK[mf][r] = min(bK[mf][r], max(a0, key));
            }
        }

        cB0 = nB0; cB1 = nB1; cB2 = nB2; cB3 = nB3;
    }

    // ---- phase B: resolve argmin per token (16-lane groups) ----
#pragma unroll
    for (int mf = 0; mf < NMF; ++mf) {
#pragma unroll
        for (int r = 0; r < 4; ++r) {
            const int a0 = aK[mf][r], b0 = bK[mf][r];
            int A = a0, B = b0;
#pragma unroll
            for (int off = 1; off < 16; off <<= 1) {
                int A2 = __shfl_xor(A, off);
                int B2 = __shfl_xor(B, off);
                int lo = min(A, A2), hi = max(A, A2);
                B = min(min(B, B2), hi);
                A = lo;
            }
            int winner = A & 1023;
            if (B - A <= WKEY) {  // contested (~3% of tokens): exact fp32 re-check
                const int t = blockTok + wv * 64 + mf * 16 + quad * 4 + r;
                float dbest = 3.4e38f;
                int ibest = 1 << 30;
                if (a0 <= A + WKEY) {
                    int e = a0 & 1023;
                    float d = exact_dist(z, emb, t, e);
                    if (d < dbest || (d == dbest && e < ibest)) { dbest = d; ibest = e; }
                }
                if (b0 <= A + WKEY) {
                    int e = b0 & 1023;
                    float d = exact_dist(z, emb, t, e);
                    if (d < dbest || (d == dbest && e < ibest)) { dbest = d; ibest = e; }
                }
#pragma unroll
                for (int off = 1; off < 16; off <<= 1) {
                    float d2 = __shfl_xor(dbest, off);
                    int i2 = __shfl_xor(ibest, off);
                    if (d2 < dbest || (d2 == dbest && i2 < ibest)) { dbest = d2; ibest = i2; }
                }
                winner = ibest;
            }
            if (col == 0) idx_lds[wv * 64 + mf * 16 + quad * 4 + r] = winner;
        }
    }

    __syncthreads();

    // ---- outputs ----
    idx_out[blockTok + tid] = (float)idx_lds[tid];
    const float4* emb_f4 = (const float4*)emb;
    float4* zq_f4 = (float4*)zq_out;
#pragma unroll
    for (int i = 0; i < MBLK * 16 / TPB; ++i) {  // 16 iters
        int item = tid + i * TPB;
        int tl = item >> 4, f4 = item & 15;
        int wi = idx_lds[tl];
        zq_f4[(size_t)(blockTok + tl) * 16 + f4] = emb_f4[(size_t)wi * 16 + f4];
    }
}

extern "C" void kernel_launch(void* const* d_in, const int* in_sizes, int n_in,
                              void* d_out, int out_size, void* d_ws, size_t ws_size,
                              hipStream_t stream) {
    const float* z = (const float*)d_in[0];
    const float* emb = (const float*)d_in[1];
    float* out = (float*)d_out;
    float* zq = out;                       // 131072*64 floats
    float* idx = out + (size_t)NTOK * ED;  // 131072 floats

    // ws layout: s2s (4KB) | bfH (128KB) | bfL (128KB)
    char* ws = (char*)d_ws;
    float* s2s = (float*)ws;
    unsigned short* bfH = (unsigned short*)(ws + 4096);
    unsigned short* bfL = (unsigned short*)(ws + 4096 + 131072);

    vq_prep<<<64, 128, 0, stream>>>(emb, bfH, bfL, s2s);
    vq_main<<<NTOK / MBLK, TPB, 0, stream>>>(z, emb, bfH, bfL, s2s, zq, idx);
}

// Round 8
// 137.440 us; speedup vs baseline: 1.1165x; 1.0624x over previous
//
#include <hip/hip_runtime.h>

typedef short short8 __attribute__((ext_vector_type(8)));
typedef float f32x4 __attribute__((ext_vector_type(4)));

#define NTOK (8 * 16 * 32 * 32)  // 131072 tokens
#define NE 1024
#define ED 64
#define TPB 256
#define MBLK 256                 // tokens per block = 4 waves x 64
#define NMF 4                    // m-frags per wave (64 tokens)
#define WKEY (1 << 19)           // candidate window: 2^-7 = 7.8e-3 in dist units
                                 // (~34 sigma of the 2-product approx error)
#define SCALE (-131072.0f)       // -2^17: exact po2 scale — applied to B ONLY

__device__ __forceinline__ unsigned short bf16_rtne(float f) {
    unsigned u = __float_as_uint(f);
    return (unsigned short)((u + 0x7FFFu + ((u >> 16) & 1u)) >> 16);
}
__device__ __forceinline__ float bf16_to_f32(unsigned short h) {
    return __uint_as_float(((unsigned)h) << 16);
}

// EXACT distance — identical structure/order to the R1 kernel (absmax 0 vs numpy).
__device__ float exact_dist(const float* __restrict__ z, const float* __restrict__ emb,
                            int t, int e) {
    const float* zt = z + (size_t)t * ED;
    const float* ep = emb + (size_t)e * ED;
    float r0 = 0.f, r1 = 0.f, r2 = 0.f, r3 = 0.f;
    float r4 = 0.f, r5 = 0.f, r6 = 0.f, r7 = 0.f;
    for (int d = 0; d < ED; d += 8) {
        r0 += zt[d + 0] * zt[d + 0];
        r1 += zt[d + 1] * zt[d + 1];
        r2 += zt[d + 2] * zt[d + 2];
        r3 += zt[d + 3] * zt[d + 3];
        r4 += zt[d + 4] * zt[d + 4];
        r5 += zt[d + 5] * zt[d + 5];
        r6 += zt[d + 6] * zt[d + 6];
        r7 += zt[d + 7] * zt[d + 7];
    }
    float s1 = ((r0 + r1) + (r2 + r3)) + ((r4 + r5) + (r6 + r7));
    float q0 = 0.f, q1 = 0.f, q2 = 0.f, q3 = 0.f;
    float q4 = 0.f, q5 = 0.f, q6 = 0.f, q7 = 0.f;
    for (int d = 0; d < ED; d += 8) {
        float v0 = ep[d + 0], v1 = ep[d + 1], v2 = ep[d + 2], v3 = ep[d + 3];
        float v4 = ep[d + 4], v5 = ep[d + 5], v6 = ep[d + 6], v7 = ep[d + 7];
        q0 += v0 * v0; q1 += v1 * v1; q2 += v2 * v2; q3 += v3 * v3;
        q4 += v4 * v4; q5 += v5 * v5; q6 += v6 * v6; q7 += v7 * v7;
    }
    float s2 = ((q0 + q1) + (q2 + q3)) + ((q4 + q5) + (q6 + q7));
    float a0 = 0.f, a1 = 0.f, a2 = 0.f, a3 = 0.f;
    for (int d = 0; d < ED; d += 4) {
        a0 = fmaf(zt[d + 0], ep[d + 0], a0);
        a1 = fmaf(zt[d + 1], ep[d + 1], a1);
        a2 = fmaf(zt[d + 2], ep[d + 2], a2);
        a3 = fmaf(zt[d + 3], ep[d + 3], a3);
    }
    float g = (a0 + a1) + (a2 + a3);
    return (s1 + s2) - 2.0f * g;
}

// ---- prep: B-fragments (bf16 HI only, -2^17-scaled, MFMA order) + scaled s2.
//      The B-lo stream is gone: A stays exact (hi+lo), so the approx error is
//      only B's bf16 rounding (~2.3e-4 std in dist) — WKEY covers it 34x. ----
__global__ __launch_bounds__(128) void vq_prep(
    const float* __restrict__ emb,
    unsigned short* __restrict__ bfH,
    float* __restrict__ s2s)
{
    const int f = blockIdx.x * 128 + threadIdx.x;  // 0..8191 fragment id
    const int col = f & 15;
    const int quad = (f >> 4) & 3;
    const int kb = (f >> 6) & 1;
    const int nt = f >> 7;
    const int e = nt * 16 + col;
    const int k0 = kb * 32 + quad * 8;

    const float* p = emb + (size_t)e * ED + k0;
    float4 v0 = *(const float4*)p;
    float4 v1 = *(const float4*)(p + 4);
    float vs[8] = {v0.x, v0.y, v0.z, v0.w, v1.x, v1.y, v1.z, v1.w};
    short8 h;
#pragma unroll
    for (int j = 0; j < 8; ++j) {
        float x = vs[j] * SCALE;              // exact po2 scaling (B side only!)
        h[j] = (short)bf16_rtne(x);
    }
    *(short8*)&bfH[(size_t)f * 8] = h;

    if (f < 4096) {
        const int row = f >> 2;
        const float4* rp = (const float4*)(emb + (size_t)row * ED + (f & 3) * 16);
        float4 a = rp[0], b = rp[1], c = rp[2], d = rp[3];
        float s = a.x * a.x + a.y * a.y + a.z * a.z + a.w * a.w
                + b.x * b.x + b.y * b.y + b.z * b.z + b.w * b.w
                + c.x * c.x + c.y * c.y + c.z * c.z + c.w * c.w
                + d.x * d.x + d.y * d.y + d.z * d.z + d.w * d.w;
        s += __shfl_xor(s, 1);
        s += __shfl_xor(s, 2);
        if ((f & 3) == 0) s2s[row] = s * 65536.0f;
    }
}

// ---- main: R2 config (best measured) with the 2-product scheme.
//      Per iter: 16 MFMA (was 24), 2 B-loads (was 4), key = cvt + v_mad_i32_i24
//      + min + med3 (was cvt/mul/add/min/med3). A = z exact (bf16 hi+lo),
//      B = bf16 hi only; error absorbed by the widened WKEY window; the exact
//      fp32 recheck (unchanged) decides every contested token. ----
__global__ void __launch_bounds__(TPB) vq_main(
    const float* __restrict__ z,
    const float* __restrict__ emb,
    const unsigned short* __restrict__ bfH,
    const float* __restrict__ s2s_g,
    float* __restrict__ zq_out,
    float* __restrict__ idx_out)
{
    __shared__ float s2L[NE];
    __shared__ int idx_lds[MBLK];

    const int tid = threadIdx.x;
    const int lane = tid & 63;
    const int wv = __builtin_amdgcn_readfirstlane(tid >> 6);
    const int col = lane & 15;
    const int quad = lane >> 4;
    const int blockTok = blockIdx.x * MBLK;

    for (int i = tid; i < NE; i += TPB) s2L[i] = s2s_g[i];

    // ---- A-fragments: 64 tokens per wave (4 m-frags), hi/lo bf16, UNSCALED ----
    short8 Ah[NMF][2], Al[NMF][2];
#pragma unroll
    for (int mf = 0; mf < NMF; ++mf) {
#pragma unroll
        for (int kf = 0; kf < 2; ++kf) {
            const float* zp = z + (size_t)(blockTok + wv * 64 + mf * 16 + col) * ED
                              + kf * 32 + quad * 8;
            float4 v0 = *(const float4*)zp;
            float4 v1 = *(const float4*)(zp + 4);
            float vs[8] = {v0.x, v0.y, v0.z, v0.w, v1.x, v1.y, v1.z, v1.w};
            short8 h, l;
#pragma unroll
            for (int j = 0; j < 8; ++j) {
                float x = vs[j];              // NO scale on A
                unsigned short hb = bf16_rtne(x);
                float hf = bf16_to_f32(hb);
                unsigned short lb = bf16_rtne(x - hf);
                h[j] = (short)hb;
                l[j] = (short)lb;
            }
            Ah[mf][kf] = h;
            Al[mf][kf] = l;
        }
    }

    int aK[NMF][4], bK[NMF][4];
#pragma unroll
    for (int mf = 0; mf < NMF; ++mf)
#pragma unroll
        for (int r = 0; r < 4; ++r) { aK[mf][r] = 0x7FFFFFFF; bK[mf][r] = 0x7FFFFFFF; }

    // B-fragment stream: per nt-slice, 128 fragments of 16B; lane's frags are
    // u4[nt*128 + lane] (k-frag 0) and u4[nt*128 + 64 + lane] (k-frag 1).
    const uint4* u4H = (const uint4*)bfH;

    // prologue: load slice 0
    uint4 cB0 = u4H[lane];
    uint4 cB1 = u4H[64 + lane];

    __syncthreads();  // s2L ready (only barrier before the epilogue)

    for (int nt = 0; nt < 64; ++nt) {
        // prefetch next slice (wrap: redundant re-load of slice 0, never consumed)
        const int nb = (((nt + 1) & 63) << 7) + lane;
        uint4 nB0 = u4H[nb];
        uint4 nB1 = u4H[nb + 64];

        short8 Bh0 = __builtin_bit_cast(short8, cB0);
        short8 Bh1 = __builtin_bit_cast(short8, cB1);

        const float s2v = s2L[nt * 16 + col];
        const int e = nt * 16 + col;
#pragma unroll
        for (int mf = 0; mf < NMF; ++mf) {
            f32x4 cc = {s2v, s2v, s2v, s2v};  // acc = s2*2^16 + A·(-2^17 e) = 2^16(s2-2g)
            cc = __builtin_amdgcn_mfma_f32_16x16x32_bf16(Ah[mf][0], Bh0, cc, 0, 0, 0);
            cc = __builtin_amdgcn_mfma_f32_16x16x32_bf16(Ah[mf][1], Bh1, cc, 0, 0, 0);
            cc = __builtin_amdgcn_mfma_f32_16x16x32_bf16(Al[mf][0], Bh0, cc, 0, 0, 0);
            cc = __builtin_amdgcn_mfma_f32_16x16x32_bf16(Al[mf][1], Bh1, cc, 0, 0, 0);
#pragma unroll
            for (int r = 0; r < 4; ++r) {
                // key = int(cc)*1024 + e — int(cc) <= 2^17 fits i24 exactly
                int ci = (int)cc[r];
                int key;
                asm("v_mad_i32_i24 %0, %1, %2, %3"
                    : "=v"(key) : "v"(ci), "s"(1024), "v"(e));
                const int a0 = aK[mf][r];
                int t1 = min(a0, key);
                // bK' = min(bK, max(a0, key)) == med3(a0, bK, key) since a0<=bK
                int med;
                asm("v_med3_i32 %0, %1, %2, %3"
                    : "=v"(med) : "v"(a0), "v"(bK[mf][r]), "v"(key));
                bK[mf][r] = med;
                aK[mf][r] = t1;
            }
        }

        cB0 = nB0; cB1 = nB1;
    }

    // ---- phase B: resolve argmin per token (16-lane groups) ----
#pragma unroll
    for (int mf = 0; mf < NMF; ++mf) {
#pragma unroll
        for (int r = 0; r < 4; ++r) {
            const int a0 = aK[mf][r], b0 = bK[mf][r];
            int A = a0, B = b0;
#pragma unroll
            for (int off = 1; off < 16; off <<= 1) {
                int A2 = __shfl_xor(A, off);
                int B2 = __shfl_xor(B, off);
                int lo = min(A, A2), hi = max(A, A2);
                B = min(min(B, B2), hi);
                A = lo;
            }
            int winner = A & 1023;
            if (B - A <= WKEY) {  // contested (~6% of tokens): exact fp32 re-check
                const int t = blockTok + wv * 64 + mf * 16 + quad * 4 + r;
                float dbest = 3.4e38f;
                int ibest = 1 << 30;
                if (a0 <= A + WKEY) {
                    int e = a0 & 1023;
                    float d = exact_dist(z, emb, t, e);
                    if (d < dbest || (d == dbest && e < ibest)) { dbest = d; ibest = e; }
                }
                if (b0 <= A + WKEY) {
                    int e = b0 & 1023;
                    float d = exact_dist(z, emb, t, e);
                    if (d < dbest || (d == dbest && e < ibest)) { dbest = d; ibest = e; }
                }
#pragma unroll
                for (int off = 1; off < 16; off <<= 1) {
                    float d2 = __shfl_xor(dbest, off);
                    int i2 = __shfl_xor(ibest, off);
                    if (d2 < dbest || (d2 == dbest && i2 < ibest)) { dbest = d2; ibest = i2; }
                }
                winner = ibest;
            }
            if (col == 0) idx_lds[wv * 64 + mf * 16 + quad * 4 + r] = winner;
        }
    }

    __syncthreads();

    // ---- outputs ----
    idx_out[blockTok + tid] = (float)idx_lds[tid];
    const float4* emb_f4 = (const float4*)emb;
    float4* zq_f4 = (float4*)zq_out;
#pragma unroll
    for (int i = 0; i < MBLK * 16 / TPB; ++i) {  // 16 iters
        int item = tid + i * TPB;
        int tl = item >> 4, f4 = item & 15;
        int wi = idx_lds[tl];
        zq_f4[(size_t)(blockTok + tl) * 16 + f4] = emb_f4[(size_t)wi * 16 + f4];
    }
}

extern "C" void kernel_launch(void* const* d_in, const int* in_sizes, int n_in,
                              void* d_out, int out_size, void* d_ws, size_t ws_size,
                              hipStream_t stream) {
    const float* z = (const float*)d_in[0];
    const float* emb = (const float*)d_in[1];
    float* out = (float*)d_out;
    float* zq = out;                       // 131072*64 floats
    float* idx = out + (size_t)NTOK * ED;  // 131072 floats

    // ws layout: s2s (4KB) | bfH (128KB)
    char* ws = (char*)d_ws;
    float* s2s = (float*)ws;
    unsigned short* bfH = (unsigned short*)(ws + 4096);

    vq_prep<<<64, 128, 0, stream>>>(emb, bfH, s2s);
    vq_main<<<NTOK / MBLK, TPB, 0, stream>>>(z, emb, bfH, s2s, zq, idx);
}

// Round 9
// 130.897 us; speedup vs baseline: 1.1723x; 1.0500x over previous
//
#include <hip/hip_runtime.h>

typedef short short8 __attribute__((ext_vector_type(8)));
typedef float f32x4 __attribute__((ext_vector_type(4)));

#define NTOK (8 * 16 * 32 * 32)  // 131072 tokens
#define NE 1024
#define ED 64
#define TPB 256
#define MBLK 256                 // tokens per block = 4 waves x 64
#define NMF 4                    // m-frags per wave (64 tokens)
#define WKEY (1 << 19)           // candidate window: 7.8e-3 in dist units
                                 // (~10.5 sigma of the pure-bf16 approx error)
#define SCALE (-131072.0f)       // -2^17: exact po2 scale — applied to B ONLY

__device__ __forceinline__ unsigned short bf16_rtne(float f) {
    unsigned u = __float_as_uint(f);
    return (unsigned short)((u + 0x7FFFu + ((u >> 16) & 1u)) >> 16);
}

// EXACT distance — identical structure/order to the R1 kernel (absmax 0 vs numpy).
__device__ float exact_dist(const float* __restrict__ z, const float* __restrict__ emb,
                            int t, int e) {
    const float* zt = z + (size_t)t * ED;
    const float* ep = emb + (size_t)e * ED;
    float r0 = 0.f, r1 = 0.f, r2 = 0.f, r3 = 0.f;
    float r4 = 0.f, r5 = 0.f, r6 = 0.f, r7 = 0.f;
    for (int d = 0; d < ED; d += 8) {
        r0 += zt[d + 0] * zt[d + 0];
        r1 += zt[d + 1] * zt[d + 1];
        r2 += zt[d + 2] * zt[d + 2];
        r3 += zt[d + 3] * zt[d + 3];
        r4 += zt[d + 4] * zt[d + 4];
        r5 += zt[d + 5] * zt[d + 5];
        r6 += zt[d + 6] * zt[d + 6];
        r7 += zt[d + 7] * zt[d + 7];
    }
    float s1 = ((r0 + r1) + (r2 + r3)) + ((r4 + r5) + (r6 + r7));
    float q0 = 0.f, q1 = 0.f, q2 = 0.f, q3 = 0.f;
    float q4 = 0.f, q5 = 0.f, q6 = 0.f, q7 = 0.f;
    for (int d = 0; d < ED; d += 8) {
        float v0 = ep[d + 0], v1 = ep[d + 1], v2 = ep[d + 2], v3 = ep[d + 3];
        float v4 = ep[d + 4], v5 = ep[d + 5], v6 = ep[d + 6], v7 = ep[d + 7];
        q0 += v0 * v0; q1 += v1 * v1; q2 += v2 * v2; q3 += v3 * v3;
        q4 += v4 * v4; q5 += v5 * v5; q6 += v6 * v6; q7 += v7 * v7;
    }
    float s2 = ((q0 + q1) + (q2 + q3)) + ((q4 + q5) + (q6 + q7));
    float a0 = 0.f, a1 = 0.f, a2 = 0.f, a3 = 0.f;
    for (int d = 0; d < ED; d += 4) {
        a0 = fmaf(zt[d + 0], ep[d + 0], a0);
        a1 = fmaf(zt[d + 1], ep[d + 1], a1);
        a2 = fmaf(zt[d + 2], ep[d + 2], a2);
        a3 = fmaf(zt[d + 3], ep[d + 3], a3);
    }
    float g = (a0 + a1) + (a2 + a3);
    return (s1 + s2) - 2.0f * g;
}

// ---- prep: B-fragments (bf16 HI only, -2^17-scaled, MFMA order) + scaled s2 ----
__global__ __launch_bounds__(128) void vq_prep(
    const float* __restrict__ emb,
    unsigned short* __restrict__ bfH,
    float* __restrict__ s2s)
{
    const int f = blockIdx.x * 128 + threadIdx.x;  // 0..8191 fragment id
    const int col = f & 15;
    const int quad = (f >> 4) & 3;
    const int kb = (f >> 6) & 1;
    const int nt = f >> 7;
    const int e = nt * 16 + col;
    const int k0 = kb * 32 + quad * 8;

    const float* p = emb + (size_t)e * ED + k0;
    float4 v0 = *(const float4*)p;
    float4 v1 = *(const float4*)(p + 4);
    float vs[8] = {v0.x, v0.y, v0.z, v0.w, v1.x, v1.y, v1.z, v1.w};
    short8 h;
#pragma unroll
    for (int j = 0; j < 8; ++j) {
        float x = vs[j] * SCALE;              // exact po2 scaling (B side only!)
        h[j] = (short)bf16_rtne(x);
    }
    *(short8*)&bfH[(size_t)f * 8] = h;

    if (f < 4096) {
        const int row = f >> 2;
        const float4* rp = (const float4*)(emb + (size_t)row * ED + (f & 3) * 16);
        float4 a = rp[0], b = rp[1], c = rp[2], d = rp[3];
        float s = a.x * a.x + a.y * a.y + a.z * a.z + a.w * a.w
                + b.x * b.x + b.y * b.y + b.z * b.z + b.w * b.w
                + c.x * c.x + c.y * c.y + c.z * c.z + c.w * c.w
                + d.x * d.x + d.y * d.y + d.z * d.z + d.w * d.w;
        s += __shfl_xor(s, 1);
        s += __shfl_xor(s, 2);
        if ((f & 3) == 0) s2s[row] = s * 65536.0f;
    }
}

// ---- main: pure bf16 x bf16 approx pass — 8 MFMA/iter (was 16).
//      R8 calibration: MFMA time is additive on the critical path, so each
//      removed MFMA pays in full. A = bf16(z) (hi only), B = bf16 hi only;
//      combined rounding error ~5.2e-4 std in dist units, WKEY window covers
//      candidate-pair error at 10.5 sigma. The exact fp32 recheck (unchanged)
//      decides every contested token -> absmax 0. setprio wraps the MFMA
//      block (free-running waves = the regime where it measured +4-7%). ----
__global__ void __launch_bounds__(TPB) vq_main(
    const float* __restrict__ z,
    const float* __restrict__ emb,
    const unsigned short* __restrict__ bfH,
    const float* __restrict__ s2s_g,
    float* __restrict__ zq_out,
    float* __restrict__ idx_out)
{
    __shared__ float s2L[NE];
    __shared__ int idx_lds[MBLK];

    const int tid = threadIdx.x;
    const int lane = tid & 63;
    const int wv = __builtin_amdgcn_readfirstlane(tid >> 6);
    const int col = lane & 15;
    const int quad = lane >> 4;
    const int blockTok = blockIdx.x * MBLK;

    for (int i = tid; i < NE; i += TPB) s2L[i] = s2s_g[i];

    // ---- A-fragments: 64 tokens per wave (4 m-frags), bf16 hi only, UNSCALED ----
    short8 Ah[NMF][2];
#pragma unroll
    for (int mf = 0; mf < NMF; ++mf) {
#pragma unroll
        for (int kf = 0; kf < 2; ++kf) {
            const float* zp = z + (size_t)(blockTok + wv * 64 + mf * 16 + col) * ED
                              + kf * 32 + quad * 8;
            float4 v0 = *(const float4*)zp;
            float4 v1 = *(const float4*)(zp + 4);
            float vs[8] = {v0.x, v0.y, v0.z, v0.w, v1.x, v1.y, v1.z, v1.w};
            short8 h;
#pragma unroll
            for (int j = 0; j < 8; ++j) h[j] = (short)bf16_rtne(vs[j]);
            Ah[mf][kf] = h;
        }
    }

    int aK[NMF][4], bK[NMF][4];
#pragma unroll
    for (int mf = 0; mf < NMF; ++mf)
#pragma unroll
        for (int r = 0; r < 4; ++r) { aK[mf][r] = 0x7FFFFFFF; bK[mf][r] = 0x7FFFFFFF; }

    // B-fragment stream: per nt-slice, 128 fragments of 16B; lane's frags are
    // u4[nt*128 + lane] (k-frag 0) and u4[nt*128 + 64 + lane] (k-frag 1).
    const uint4* u4H = (const uint4*)bfH;

    // prologue: load slice 0
    uint4 cB0 = u4H[lane];
    uint4 cB1 = u4H[64 + lane];

    __syncthreads();  // s2L ready (only barrier before the epilogue)

    for (int nt = 0; nt < 64; ++nt) {
        // prefetch next slice (wrap: redundant re-load of slice 0, never consumed)
        const int nb = (((nt + 1) & 63) << 7) + lane;
        uint4 nB0 = u4H[nb];
        uint4 nB1 = u4H[nb + 64];

        short8 Bh0 = __builtin_bit_cast(short8, cB0);
        short8 Bh1 = __builtin_bit_cast(short8, cB1);

        const float s2v = s2L[nt * 16 + col];
        const int e = nt * 16 + col;

        f32x4 cc[NMF];
        __builtin_amdgcn_s_setprio(1);
#pragma unroll
        for (int mf = 0; mf < NMF; ++mf) {
            f32x4 c0 = {s2v, s2v, s2v, s2v};  // acc = s2*2^16 + A·(-2^17 e) = 2^16(s2-2g)
            c0 = __builtin_amdgcn_mfma_f32_16x16x32_bf16(Ah[mf][0], Bh0, c0, 0, 0, 0);
            c0 = __builtin_amdgcn_mfma_f32_16x16x32_bf16(Ah[mf][1], Bh1, c0, 0, 0, 0);
            cc[mf] = c0;
        }
        __builtin_amdgcn_s_setprio(0);

#pragma unroll
        for (int mf = 0; mf < NMF; ++mf) {
#pragma unroll
            for (int r = 0; r < 4; ++r) {
                // key = int(cc)*1024 + e — int(cc) <= ~2^17 fits i24 exactly
                int ci = (int)cc[mf][r];
                int key;
                asm("v_mad_i32_i24 %0, %1, %2, %3"
                    : "=v"(key) : "v"(ci), "s"(1024), "v"(e));
                const int a0 = aK[mf][r];
                int t1 = min(a0, key);
                // bK' = min(bK, max(a0, key)) == med3(a0, bK, key) since a0<=bK
                int med;
                asm("v_med3_i32 %0, %1, %2, %3"
                    : "=v"(med) : "v"(a0), "v"(bK[mf][r]), "v"(key));
                bK[mf][r] = med;
                aK[mf][r] = t1;
            }
        }

        cB0 = nB0; cB1 = nB1;
    }

    // ---- phase B: resolve argmin per token (16-lane groups) ----
#pragma unroll
    for (int mf = 0; mf < NMF; ++mf) {
#pragma unroll
        for (int r = 0; r < 4; ++r) {
            const int a0 = aK[mf][r], b0 = bK[mf][r];
            int A = a0, B = b0;
#pragma unroll
            for (int off = 1; off < 16; off <<= 1) {
                int A2 = __shfl_xor(A, off);
                int B2 = __shfl_xor(B, off);
                int lo = min(A, A2), hi = max(A, A2);
                B = min(min(B, B2), hi);
                A = lo;
            }
            int winner = A & 1023;
            if (B - A <= WKEY) {  // contested: exact fp32 re-check of candidates
                const int t = blockTok + wv * 64 + mf * 16 + quad * 4 + r;
                float dbest = 3.4e38f;
                int ibest = 1 << 30;
                if (a0 <= A + WKEY) {
                    int e = a0 & 1023;
                    float d = exact_dist(z, emb, t, e);
                    if (d < dbest || (d == dbest && e < ibest)) { dbest = d; ibest = e; }
                }
                if (b0 <= A + WKEY) {
                    int e = b0 & 1023;
                    float d = exact_dist(z, emb, t, e);
                    if (d < dbest || (d == dbest && e < ibest)) { dbest = d; ibest = e; }
                }
#pragma unroll
                for (int off = 1; off < 16; off <<= 1) {
                    float d2 = __shfl_xor(dbest, off);
                    int i2 = __shfl_xor(ibest, off);
                    if (d2 < dbest || (d2 == dbest && i2 < ibest)) { dbest = d2; ibest = i2; }
                }
                winner = ibest;
            }
            if (col == 0) idx_lds[wv * 64 + mf * 16 + quad * 4 + r] = winner;
        }
    }

    __syncthreads();

    // ---- outputs ----
    idx_out[blockTok + tid] = (float)idx_lds[tid];
    const float4* emb_f4 = (const float4*)emb;
    float4* zq_f4 = (float4*)zq_out;
#pragma unroll
    for (int i = 0; i < MBLK * 16 / TPB; ++i) {  // 16 iters
        int item = tid + i * TPB;
        int tl = item >> 4, f4 = item & 15;
        int wi = idx_lds[tl];
        zq_f4[(size_t)(blockTok + tl) * 16 + f4] = emb_f4[(size_t)wi * 16 + f4];
    }
}

extern "C" void kernel_launch(void* const* d_in, const int* in_sizes, int n_in,
                              void* d_out, int out_size, void* d_ws, size_t ws_size,
                              hipStream_t stream) {
    const float* z = (const float*)d_in[0];
    const float* emb = (const float*)d_in[1];
    float* out = (float*)d_out;
    float* zq = out;                       // 131072*64 floats
    float* idx = out + (size_t)NTOK * ED;  // 131072 floats

    // ws layout: s2s (4KB) | bfH (128KB)
    char* ws = (char*)d_ws;
    float* s2s = (float*)ws;
    unsigned short* bfH = (unsigned short*)(ws + 4096);

    vq_prep<<<64, 128, 0, stream>>>(emb, bfH, s2s);
    vq_main<<<NTOK / MBLK, TPB, 0, stream>>>(z, emb, bfH, s2s, zq, idx);
}